// Round 2
// baseline (265.773 us; speedup 1.0000x reference)
//
#include <hip/hip_runtime.h>

#define BB 32
#define LL 2048
#define DD 768
#define VV 32000
#define COLS 32            // columns owned per pool block
#define DSEG (DD / COLS)   // 24 column segments

// ---------------------------------------------------------------------------
// K1: one 512-thread block per row (grid=32). O(L) via LDS histogram:
// 32000 16-bit counters packed 2-per-u32 (64000 B). Each thread owns 4
// contiguous tokens (one int4 load each for ids/mask). Scan is wave-shuffle
// based: 3 barriers total. idf gather hoisted to overlap histogram phase.
// (R4: no longer zeroes out[] — K2 now writes every element exactly once.)
// ---------------------------------------------------------------------------
__global__ __launch_bounds__(512) void weights_kernel(
    const int* __restrict__ ids, const int* __restrict__ mask,
    const float* __restrict__ idf, const float* __restrict__ alpha_p,
    float* __restrict__ wc, int* __restrict__ lc,
    int* __restrict__ nv_ws, float* __restrict__ inv_ws)
{
    __shared__ unsigned int hist[VV / 2];   // 64000 B, packed 2x16-bit counts
    __shared__ int   wtot[8];
    __shared__ float wsum_s[8];

    const int tid  = threadIdx.x;
    const int lane = tid & 63, wave = tid >> 6;     // 8 waves
    const int b    = blockIdx.x;

    for (int i = tid; i < VV / 2; i += 512) hist[i] = 0u;

    const int4 ia = ((const int4*)(ids  + b * LL))[tid];
    const int4 ma = ((const int4*)(mask + b * LL))[tid];
    const int idv[4] = {ia.x, ia.y, ia.z, ia.w};
    const int mv[4]  = {ma.x, ma.y, ma.z, ma.w};

    // Hoisted idf gather — latency overlaps hist zero + atomics below.
    float idfv[4];
    #pragma unroll
    for (int k = 0; k < 4; ++k) idfv[k] = idf[idv[k]];

    __syncthreads();                        // barrier 1: hist zeroed

    int c_t = 0;
    #pragma unroll
    for (int k = 0; k < 4; ++k) {
        if (mv[k]) {
            atomicAdd(&hist[idv[k] >> 1], 1u << ((idv[k] & 1) * 16));
            c_t++;
        }
    }

    // Wave-level inclusive scan of c_t (no barriers).
    int incl = c_t;
    #pragma unroll
    for (int off = 1; off < 64; off <<= 1) {
        const int n = __shfl_up(incl, off, 64);
        if (lane >= off) incl += n;
    }
    if (lane == 63) wtot[wave] = incl;
    __syncthreads();                        // barrier 2: orders hist atomics + wtot

    int wpre = 0, total_valid = 0;
    #pragma unroll
    for (int w = 0; w < 8; ++w) {
        const int t = wtot[w];
        if (w < wave) wpre += t;
        total_valid += t;
    }
    const int excl = wpre + incl - c_t;

    const float nvf   = fmaxf((float)total_valid, 1.0f);
    const float alpha = alpha_p[0];

    float wsum = 0.0f;
    float wv[4];
    #pragma unroll
    for (int k = 0; k < 4; ++k) {
        const int id       = idv[k];
        const unsigned raw = hist[id >> 1];
        const int cnt      = (raw >> ((id & 1) * 16)) & 0xffff;
        const float tf     = (float)cnt / nvf;
        const float w      = (1.0f + alpha * tf * idfv[k]) * (float)(mv[k] != 0);
        wv[k] = w;
        wsum += w;
    }

    int pos = b * LL + excl;
    #pragma unroll
    for (int k = 0; k < 4; ++k) {
        if (mv[k]) { wc[pos] = wv[k]; lc[pos] = tid * 4 + k; pos++; }
    }

    // Row norm: wave shuffle-reduce, then thread 0 combines 8 wave sums.
    #pragma unroll
    for (int off = 32; off; off >>= 1) wsum += __shfl_down(wsum, off, 64);
    if (lane == 0) wsum_s[wave] = wsum;
    __syncthreads();                        // barrier 3
    if (tid == 0) {
        float t = 0.0f;
        #pragma unroll
        for (int w = 0; w < 8; ++w) t += wsum_s[w];
        inv_ws[b] = 1.0f / fmaxf(t, 1e-12f);
        nv_ws[b]  = total_valid;
    }
}

// ---------------------------------------------------------------------------
// K2 (R4 rewrite, R5 compile fix): atomic-free D-split pooling. Block (c, b)
// exclusively owns out[b, c*32 : c*32+32] — grid (24, 32) = 768 blocks,
// 256 threads, 3/CU. The row's full compacted (w, l) list is staged to LDS
// (<=16 KB), then each 8-lane group reads one token row's 128 B slice as a
// single float4/lane: every global request is exactly one full cache line.
// 4-deep unroll keeps 4 lines in flight per lane-group. Epilogue is a
// 3-step shfl_xor reduce + one direct float4 store with 1/norm folded in —
// no atomics, no pre-zeroed out[], no NSEG imbalance.
// ---------------------------------------------------------------------------
__device__ __forceinline__ void fma4(float4& acc, const float4 v, const float s)
{
    acc.x = fmaf(v.x, s, acc.x);
    acc.y = fmaf(v.y, s, acc.y);
    acc.z = fmaf(v.z, s, acc.z);
    acc.w = fmaf(v.w, s, acc.w);
}

__global__ __launch_bounds__(256) void pool_kernel(
    const float* __restrict__ h, const float* __restrict__ wc,
    const int* __restrict__ lc, const int* __restrict__ nv_ws,
    const float* __restrict__ inv_ws, float* __restrict__ out)
{
    __shared__ float  w_s[LL];      // 8 KB (worst case nv = 2048)
    __shared__ int    l_s[LL];      // 8 KB
    __shared__ float4 red4[4][8];   // per-wave col-quad partials

    const int tid  = threadIdx.x;
    const int wave = tid >> 6, lane = tid & 63;
    const int b    = blockIdx.y;
    const int c0   = blockIdx.x * COLS;

    const int nv = nv_ws[b];
    for (int i = tid; i < nv; i += 256) {
        w_s[i] = wc[b * LL + i];
        l_s[i] = lc[b * LL + i];
    }
    __syncthreads();

    // lane layout: 8 token-groups x 8 col-quads. Each lane loads one float4
    // (16 B) of its token's 128 B column slice — request = one cache line
    // per 8-lane group, fully coalesced.
    const float* hb = h + (size_t)b * (LL * DD) + c0 + (lane & 7) * 4;
    const int g = wave * 8 + (lane >> 3);   // token slot 0..31 within block

    float4 acc = {0.f, 0.f, 0.f, 0.f};
    int t = g;
    for (; t + 96 < nv; t += 128) {         // 4-deep unroll: 4 lines in flight
        const float wA = w_s[t];      const int lA = l_s[t];
        const float wB = w_s[t + 32]; const int lB = l_s[t + 32];
        const float wC = w_s[t + 64]; const int lC = l_s[t + 64];
        const float wD = w_s[t + 96]; const int lD = l_s[t + 96];
        const float4 vA = *(const float4*)(hb + (size_t)lA * DD);
        const float4 vB = *(const float4*)(hb + (size_t)lB * DD);
        const float4 vC = *(const float4*)(hb + (size_t)lC * DD);
        const float4 vD = *(const float4*)(hb + (size_t)lD * DD);
        fma4(acc, vA, wA); fma4(acc, vB, wB);
        fma4(acc, vC, wC); fma4(acc, vD, wD);
    }
    for (; t < nv; t += 32) {
        const float w = w_s[t]; const int l = l_s[t];
        const float4 v = *(const float4*)(hb + (size_t)l * DD);
        fma4(acc, v, w);
    }

    // Reduce across the 8 token-groups (lanes q, q+8, ..., q+56 share cols).
    #pragma unroll
    for (int off = 8; off < 64; off <<= 1) {
        acc.x += __shfl_xor(acc.x, off, 64);
        acc.y += __shfl_xor(acc.y, off, 64);
        acc.z += __shfl_xor(acc.z, off, 64);
        acc.w += __shfl_xor(acc.w, off, 64);
    }
    if (lane < 8) red4[wave][lane] = acc;
    __syncthreads();

    if (tid < 8) {
        const float4 r0 = red4[0][tid], r1 = red4[1][tid];
        const float4 r2 = red4[2][tid], r3 = red4[3][tid];
        const float inv = inv_ws[b];
        float4 r;
        r.x = (r0.x + r1.x + r2.x + r3.x) * inv;
        r.y = (r0.y + r1.y + r2.y + r3.y) * inv;
        r.z = (r0.z + r1.z + r2.z + r3.z) * inv;
        r.w = (r0.w + r1.w + r2.w + r3.w) * inv;
        ((float4*)(out + b * DD + c0))[tid] = r;   // exclusive, no atomics
    }
}

extern "C" void kernel_launch(void* const* d_in, const int* in_sizes, int n_in,
                              void* d_out, int out_size, void* d_ws, size_t ws_size,
                              hipStream_t stream)
{
    const float* h     = (const float*)d_in[0];   // [B,L,D] fp32
    const int*   mask  = (const int*)  d_in[1];   // [B,L]
    const int*   ids   = (const int*)  d_in[2];   // [B,L]
    const float* idf   = (const float*)d_in[3];   // [V]
    const float* alpha = (const float*)d_in[4];   // scalar
    float*       out   = (float*)d_out;           // [B,D]

    float* wc  = (float*)d_ws;                    // B*L floats
    int*   lc  = (int*)(wc + BB * LL);            // B*L ints
    int*   nv  = lc + BB * LL;                    // B ints
    float* inv = (float*)(nv + BB);               // B floats

    weights_kernel<<<BB, 512, 0, stream>>>(ids, mask, idf, alpha, wc, lc, nv, inv);
    pool_kernel<<<dim3(DSEG, BB), 256, 0, stream>>>(h, wc, lc, nv, inv, out);
}